// Round 2
// baseline (1615.321 us; speedup 1.0000x reference)
//
#include <hip/hip_runtime.h>
#include <hip/hip_bf16.h>

typedef unsigned short u16;
typedef unsigned int u32;
typedef __attribute__((ext_vector_type(4))) float f32x4;
typedef __attribute__((ext_vector_type(8))) short s16x8;

#define HG_N   200000
#define HG_E   50000
#define HG_NNZ 2000000
#define HG_F   256
#define HG_D   128

__device__ __forceinline__ u32 f2bf_rne(float x) {
  u32 u = __float_as_uint(x);
  return (u + 0x7fffu + ((u >> 16) & 1u)) >> 16;
}
__device__ __forceinline__ float bf2f(u32 bits) { return __uint_as_float(bits << 16); }

// ---------------- dtype detection ----------------
// If feats is fp32, even u16 halves are random mantissa words: exponent field
// uniform over 0..255 (~90% outside [0x70,0x88]). If feats is bf16, even u16s
// are genuine N(0,1) bf16 values (exponent always inside the band).
__global__ void detect_dtype(const u16* __restrict__ f, int* __restrict__ flag) {
  __shared__ int acc[4];
  int t = threadIdx.x;
  int bad = 0;
  for (int i = t; i < 2048; i += 256) {
    u32 u = f[2 * i];
    int e = (u >> 7) & 0xff;
    if (e < 0x70 || e > 0x88) bad++;
  }
#pragma unroll
  for (int off = 32; off; off >>= 1) bad += __shfl_down(bad, off);
  if ((t & 63) == 0) acc[t >> 6] = bad;
  __syncthreads();
  if (t == 0) flag[0] = (acc[0] + acc[1] + acc[2] + acc[3] > 200) ? 1 : 0;
}

// ---------------- CSR build ----------------

__global__ void hist_kernel(const int* __restrict__ pv, const int* __restrict__ pe,
                            int* __restrict__ cntv, int* __restrict__ cnte) {
  int p = blockIdx.x * 256 + threadIdx.x;
  if (p >= HG_NNZ) return;
  atomicAdd(&cnte[pe[p]], 1);
  atomicAdd(&cntv[pv[p]], 1);
}

__global__ void scan_pass1(const int* __restrict__ in, int len, int* __restrict__ bsums) {
  __shared__ int wsum[4];
  int t = threadIdx.x;
  int base = blockIdx.x * 1024 + t * 4;
  int s = 0;
#pragma unroll
  for (int i = 0; i < 4; ++i) if (base + i < len) s += in[base + i];
#pragma unroll
  for (int off = 32; off; off >>= 1) s += __shfl_down(s, off);
  if ((t & 63) == 0) wsum[t >> 6] = s;
  __syncthreads();
  if (t == 0) bsums[blockIdx.x] = wsum[0] + wsum[1] + wsum[2] + wsum[3];
}

__global__ void scan_pass2(int* __restrict__ bsums, int len) {
  __shared__ int lds[256];
  int t = threadIdx.x;
  int v = (t < len) ? bsums[t] : 0;
  lds[t] = v;
  __syncthreads();
  for (int off = 1; off < 256; off <<= 1) {
    int x = (t >= off) ? lds[t - off] : 0;
    __syncthreads();
    lds[t] += x;
    __syncthreads();
  }
  if (t < len) bsums[t] = lds[t] - v;  // exclusive
}

__global__ void scan_pass3(const int* __restrict__ in, int len, const int* __restrict__ bsums,
                           int* __restrict__ rp, int total) {
  __shared__ int lds[256];
  int t = threadIdx.x;
  int base = blockIdx.x * 1024 + t * 4;
  int v[4], s = 0;
#pragma unroll
  for (int i = 0; i < 4; ++i) { v[i] = (base + i < len) ? in[base + i] : 0; s += v[i]; }
  lds[t] = s;
  __syncthreads();
  for (int off = 1; off < 256; off <<= 1) {
    int x = (t >= off) ? lds[t - off] : 0;
    __syncthreads();
    lds[t] += x;
    __syncthreads();
  }
  int excl = lds[t] - s + bsums[blockIdx.x];
#pragma unroll
  for (int i = 0; i < 4; ++i) {
    if (base + i < len) { rp[base + i] = excl; excl += v[i]; }
  }
  if (blockIdx.x == 0 && t == 0) rp[len] = total;
}

__global__ void build_csr(const int* __restrict__ pv, const int* __restrict__ pe,
                          const void* __restrict__ wve, const void* __restrict__ wev,
                          const int* __restrict__ rpe, const int* __restrict__ rpv,
                          int* __restrict__ cnte, int* __restrict__ cntv,
                          int* __restrict__ cole, float* __restrict__ we,
                          int* __restrict__ colv, float* __restrict__ wv,
                          const int* __restrict__ flag) {
  int p = blockIdx.x * 256 + threadIdx.x;
  if (p >= HG_NNZ) return;
  int fp32 = *flag;
  int v = pv[p], e = pe[p];
  float w1 = fp32 ? ((const float*)wve)[p] : bf2f(((const u16*)wve)[p]);
  float w2 = fp32 ? ((const float*)wev)[p] : bf2f(((const u16*)wev)[p]);
  int pos = rpe[e] + atomicAdd(&cnte[e], 1);
  cole[pos] = v;
  we[pos] = w1;
  pos = rpv[v] + atomicAdd(&cntv[v], 1);
  colv[pos] = e;
  wv[pos] = w2;
}

// ---------------- GEMM: x = feats @ W + b (bf16 MFMA, bf16 out) ----------------

__global__ void transpose_w_kernel(const void* __restrict__ W, u16* __restrict__ WT,
                                   const int* __restrict__ flag) {
  int idx = blockIdx.x * 256 + threadIdx.x;  // 256*128 = 32768 elems
  u16 v = (*flag) ? (u16)f2bf_rne(((const float*)W)[idx]) : ((const u16*)W)[idx];
  WT[(idx & 127) * 256 + (idx >> 7)] = v;
}

// One wave computes a 16-row x 128-col strip. W^T staged in 64KB LDS with a
// 16B-granule XOR swizzle (unswizzled 512B row stride = 16-way bank conflict).
template <bool FP32>
__global__ __launch_bounds__(256) void gemm_kernel(
    const void* __restrict__ A,    // feats [N][256] (bf16 or fp32 per flag)
    const u16* __restrict__ WT,    // bf16 [128][256] (W transposed, canonical)
    const void* __restrict__ bias, // [128]
    const int* __restrict__ flag,
    u16* __restrict__ xb) {        // bf16 [N][128]
  if ((*flag != 0) != FP32) return;
  __shared__ u16 wt[32768];
  {
    const uint4* src = (const uint4*)WT;  // 4096 granules, 32 per row
    uint4* d = (uint4*)wt;
    for (int i = threadIdx.x; i < 4096; i += 256) {
      int r = i >> 5, g = i & 31;
      d[(r << 5) | (g ^ (r & 31))] = src[i];
    }
  }
  __syncthreads();
  int lane = threadIdx.x & 63;
  int q = lane >> 4, m = lane & 15;
  int wave0 = blockIdx.x * 4 + (threadIdx.x >> 6);
  int nwaves = gridDim.x * 4;
  const s16x8* wlds = (const s16x8*)wt;
  for (int strip = wave0; strip < HG_N / 16; strip += nwaves) {
    f32x4 acc[8];
#pragma unroll
    for (int n = 0; n < 8; ++n) acc[n] = (f32x4){0.f, 0.f, 0.f, 0.f};
#pragma unroll
    for (int k0 = 0; k0 < 8; ++k0) {
      s16x8 a;
      if (FP32) {
        const float* ar = (const float*)A + (size_t)(strip * 16 + m) * 256 + q * 8 + k0 * 32;
        float4 p0 = *(const float4*)ar;
        float4 p1 = *(const float4*)(ar + 4);
        a[0] = (short)f2bf_rne(p0.x); a[1] = (short)f2bf_rne(p0.y);
        a[2] = (short)f2bf_rne(p0.z); a[3] = (short)f2bf_rne(p0.w);
        a[4] = (short)f2bf_rne(p1.x); a[5] = (short)f2bf_rne(p1.y);
        a[6] = (short)f2bf_rne(p1.z); a[7] = (short)f2bf_rne(p1.w);
      } else {
        a = *(const s16x8*)((const u16*)A + (size_t)(strip * 16 + m) * 256 + q * 8 + k0 * 32);
      }
      int g = (k0 << 2) | q;
#pragma unroll
      for (int n = 0; n < 8; ++n) {
        int rr = n * 16 + m;  // B col index; WT row
        s16x8 b = wlds[(rr << 5) | (g ^ (rr & 31))];  // B[k0*32+q*8+j][rr]
        acc[n] = __builtin_amdgcn_mfma_f32_16x16x32_bf16(a, b, acc[n], 0, 0, 0);
      }
    }
#pragma unroll
    for (int n = 0; n < 8; ++n) {
      float bv = FP32 ? ((const float*)bias)[n * 16 + m] : bf2f(((const u16*)bias)[n * 16 + m]);
#pragma unroll
      for (int r = 0; r < 4; ++r) {
        // C/D layout: col = lane&15, row = (lane>>4)*4 + r  [m89/m91 verified]
        xb[(size_t)(strip * 16 + q * 4 + r) * 128 + n * 16 + m] = (u16)f2bf_rne(acc[n][r] + bv);
      }
    }
  }
}

// ---------------- Pull aggregation over bf16 rows, fp32 accumulate ----------------

__global__ __launch_bounds__(256) void pull_kernel(
    const int* __restrict__ rp, const int* __restrict__ col, const float* __restrict__ wgt,
    const u32* __restrict__ src, u32* __restrict__ dst, int nrows) {
  int row = blockIdx.x * 4 + (threadIdx.x >> 6);
  if (row >= nrows) return;
  int lane = threadIdx.x & 63;
  int beg = rp[row], end = rp[row + 1];
  float ax = 0.f, ay = 0.f, den = 0.f;
  for (int j = beg; j < end; ++j) {
    int c = col[j];
    float w = wgt[j];
    u32 u = src[(size_t)c * 64 + lane];
    ax = fmaf(w, __uint_as_float(u << 16), ax);
    ay = fmaf(w, __uint_as_float(u & 0xffff0000u), ay);
    den += w;
  }
  float inv = 1.0f / fmaxf(den, 1e-12f);
  dst[(size_t)row * 64 + lane] = f2bf_rne(ax * inv) | (f2bf_rne(ay * inv) << 16);
}

// ---------------- Softmax (bf16 in, bf16/fp32 out) ----------------

template <bool FP32>
__global__ __launch_bounds__(256) void softmax_kernel(const u32* __restrict__ xb,
                                                      void* __restrict__ out,
                                                      const int* __restrict__ flag) {
  if ((*flag != 0) != FP32) return;
  int row = blockIdx.x * 4 + (threadIdx.x >> 6);
  int lane = threadIdx.x & 63;
  u32 u = xb[(size_t)row * 64 + lane];
  float v0 = __uint_as_float(u << 16);
  float v1 = __uint_as_float(u & 0xffff0000u);
  float mx = fmaxf(v0, v1);
#pragma unroll
  for (int off = 32; off; off >>= 1) mx = fmaxf(mx, __shfl_xor(mx, off));
  float e0 = __expf(v0 - mx), e1 = __expf(v1 - mx);
  float s = e0 + e1;
#pragma unroll
  for (int off = 32; off; off >>= 1) s += __shfl_xor(s, off);
  float inv = 1.0f / s;
  if (FP32) {
    float2 o; o.x = e0 * inv; o.y = e1 * inv;
    ((float2*)out)[(size_t)row * 64 + lane] = o;
  } else {
    ((u32*)out)[(size_t)row * 64 + lane] = f2bf_rne(e0 * inv) | (f2bf_rne(e1 * inv) << 16);
  }
}

// ---------------- launch ----------------

extern "C" void kernel_launch(void* const* d_in, const int* in_sizes, int n_in,
                              void* d_out, int out_size, void* d_ws, size_t ws_size,
                              hipStream_t stream) {
  const void* feats = d_in[0];
  const void* W = d_in[1];
  const void* bias = d_in[2];
  const void* wve = d_in[3];
  const void* wev = d_in[4];
  const int* pv = (const int*)d_in[5];
  const int* pe = (const int*)d_in[6];

  char* p = (char*)d_ws;
  auto alloc = [&](size_t b) { char* r = p; p += (b + 255) & ~(size_t)255; return r; };
  int* flag = (int*)alloc(4);
  u16* xb = (u16*)alloc((size_t)HG_N * HG_D * 2);   // vertex features bf16
  u16* yb = (u16*)alloc((size_t)HG_E * HG_D * 2);   // edge features bf16
  u16* wtg = (u16*)alloc(HG_D * HG_F * 2);          // canonical W^T bf16
  int* rpe = (int*)alloc((HG_E + 1) * 4);
  int* rpv = (int*)alloc((HG_N + 1) * 4);
  int* cnte = (int*)alloc(HG_E * 4);
  int* cntv = (int*)alloc(HG_N * 4);
  int* cole = (int*)alloc((size_t)HG_NNZ * 4);
  float* we = (float*)alloc((size_t)HG_NNZ * 4);
  int* colv = (int*)alloc((size_t)HG_NNZ * 4);
  float* wv = (float*)alloc((size_t)HG_NNZ * 4);
  int* bsums = (int*)alloc(4096);
  // total ~98 MB

  detect_dtype<<<1, 256, 0, stream>>>((const u16*)feats, flag);

  // CSR build
  hipMemsetAsync(cnte, 0, HG_E * 4, stream);
  hipMemsetAsync(cntv, 0, HG_N * 4, stream);
  hist_kernel<<<(HG_NNZ + 255) / 256, 256, 0, stream>>>(pv, pe, cntv, cnte);
  int be = (HG_E + 1023) / 1024, bv = (HG_N + 1023) / 1024;
  scan_pass1<<<be, 256, 0, stream>>>(cnte, HG_E, bsums);
  scan_pass2<<<1, 256, 0, stream>>>(bsums, be);
  scan_pass3<<<be, 256, 0, stream>>>(cnte, HG_E, bsums, rpe, HG_NNZ);
  scan_pass1<<<bv, 256, 0, stream>>>(cntv, HG_N, bsums);
  scan_pass2<<<1, 256, 0, stream>>>(bsums, bv);
  scan_pass3<<<bv, 256, 0, stream>>>(cntv, HG_N, bsums, rpv, HG_NNZ);
  hipMemsetAsync(cnte, 0, HG_E * 4, stream);
  hipMemsetAsync(cntv, 0, HG_N * 4, stream);
  build_csr<<<(HG_NNZ + 255) / 256, 256, 0, stream>>>(pv, pe, wve, wev, rpe, rpv,
                                                      cnte, cntv, cole, we, colv, wv, flag);

  // x = feats @ W + b
  transpose_w_kernel<<<128, 256, 0, stream>>>(W, wtg, flag);
  gemm_kernel<false><<<1024, 256, 0, stream>>>(feats, wtg, bias, flag, xb);
  gemm_kernel<true><<<1024, 256, 0, stream>>>(feats, wtg, bias, flag, xb);

  // two hops of weighted-mean aggregation (xb and yb ping-pong)
  pull_kernel<<<HG_E / 4, 256, 0, stream>>>(rpe, cole, we, (const u32*)xb, (u32*)yb, HG_E);
  pull_kernel<<<HG_N / 4, 256, 0, stream>>>(rpv, colv, wv, (const u32*)yb, (u32*)xb, HG_N);
  pull_kernel<<<HG_E / 4, 256, 0, stream>>>(rpe, cole, we, (const u32*)xb, (u32*)yb, HG_E);
  pull_kernel<<<HG_N / 4, 256, 0, stream>>>(rpv, colv, wv, (const u32*)yb, (u32*)xb, HG_N);

  softmax_kernel<false><<<HG_N / 4, 256, 0, stream>>>((const u32*)xb, d_out, flag);
  softmax_kernel<true><<<HG_N / 4, 256, 0, stream>>>((const u32*)xb, d_out, flag);
}

// Round 3
// 1153.847 us; speedup vs baseline: 1.3999x; 1.3999x over previous
//
#include <hip/hip_runtime.h>
#include <hip/hip_bf16.h>

typedef unsigned short u16;
typedef unsigned int u32;
typedef __attribute__((ext_vector_type(4))) float f32x4;
typedef __attribute__((ext_vector_type(8))) short s16x8;

#define HG_N   200000
#define HG_E   50000
#define HG_NNZ 2000000
#define HG_F   256
#define HG_D   128

__device__ __forceinline__ u32 f2bf_rne(float x) {
  u32 u = __float_as_uint(x);
  return (u + 0x7fffu + ((u >> 16) & 1u)) >> 16;
}
__device__ __forceinline__ float bf2f(u32 bits) { return __uint_as_float(bits << 16); }
__device__ __forceinline__ float bf_lo(u32 u) { return __uint_as_float(u << 16); }
__device__ __forceinline__ float bf_hi(u32 u) { return __uint_as_float(u & 0xffff0000u); }

// ---------------- dtype detection ----------------
__global__ void detect_dtype(const u16* __restrict__ f, int* __restrict__ flag) {
  __shared__ int acc[4];
  int t = threadIdx.x;
  int bad = 0;
  for (int i = t; i < 2048; i += 256) {
    u32 u = f[2 * i];
    int e = (u >> 7) & 0xff;
    if (e < 0x70 || e > 0x88) bad++;
  }
#pragma unroll
  for (int off = 32; off; off >>= 1) bad += __shfl_down(bad, off);
  if ((t & 63) == 0) acc[t >> 6] = bad;
  __syncthreads();
  if (t == 0) flag[0] = (acc[0] + acc[1] + acc[2] + acc[3] > 200) ? 1 : 0;
}

// ---------------- CSR build ----------------

__global__ void hist_kernel(const int* __restrict__ pv, const int* __restrict__ pe,
                            int* __restrict__ cntv, int* __restrict__ cnte) {
  int p = blockIdx.x * 256 + threadIdx.x;
  if (p >= HG_NNZ) return;
  atomicAdd(&cnte[pe[p]], 1);
  atomicAdd(&cntv[pv[p]], 1);
}

__global__ void scan_pass1(const int* __restrict__ in, int len, int* __restrict__ bsums) {
  __shared__ int wsum[4];
  int t = threadIdx.x;
  int base = blockIdx.x * 1024 + t * 4;
  int s = 0;
#pragma unroll
  for (int i = 0; i < 4; ++i) if (base + i < len) s += in[base + i];
#pragma unroll
  for (int off = 32; off; off >>= 1) s += __shfl_down(s, off);
  if ((t & 63) == 0) wsum[t >> 6] = s;
  __syncthreads();
  if (t == 0) bsums[blockIdx.x] = wsum[0] + wsum[1] + wsum[2] + wsum[3];
}

__global__ void scan_pass2(int* __restrict__ bsums, int len) {
  __shared__ int lds[256];
  int t = threadIdx.x;
  int v = (t < len) ? bsums[t] : 0;
  lds[t] = v;
  __syncthreads();
  for (int off = 1; off < 256; off <<= 1) {
    int x = (t >= off) ? lds[t - off] : 0;
    __syncthreads();
    lds[t] += x;
    __syncthreads();
  }
  if (t < len) bsums[t] = lds[t] - v;  // exclusive
}

__global__ void scan_pass3(const int* __restrict__ in, int len, const int* __restrict__ bsums,
                           int* __restrict__ rp, int total) {
  __shared__ int lds[256];
  int t = threadIdx.x;
  int base = blockIdx.x * 1024 + t * 4;
  int v[4], s = 0;
#pragma unroll
  for (int i = 0; i < 4; ++i) { v[i] = (base + i < len) ? in[base + i] : 0; s += v[i]; }
  lds[t] = s;
  __syncthreads();
  for (int off = 1; off < 256; off <<= 1) {
    int x = (t >= off) ? lds[t - off] : 0;
    __syncthreads();
    lds[t] += x;
    __syncthreads();
  }
  int excl = lds[t] - s + bsums[blockIdx.x];
#pragma unroll
  for (int i = 0; i < 4; ++i) {
    if (base + i < len) { rp[base + i] = excl; excl += v[i]; }
  }
  if (blockIdx.x == 0 && t == 0) rp[len] = total;
}

// Packed CSR entry: int2 {col, w_as_float_bits}. One 8B scattered store per
// incidence per direction (was 2x4B to two arrays -> 2x the line touches).
__global__ void build_csr(const int* __restrict__ pv, const int* __restrict__ pe,
                          const void* __restrict__ wve, const void* __restrict__ wev,
                          const int* __restrict__ rpe, const int* __restrict__ rpv,
                          int* __restrict__ cnte, int* __restrict__ cntv,
                          int2* __restrict__ ente, int2* __restrict__ entv,
                          const int* __restrict__ flag) {
  int p = blockIdx.x * 256 + threadIdx.x;
  if (p >= HG_NNZ) return;
  int fp32 = *flag;
  int v = pv[p], e = pe[p];
  float w1 = fp32 ? ((const float*)wve)[p] : bf2f(((const u16*)wve)[p]);
  float w2 = fp32 ? ((const float*)wev)[p] : bf2f(((const u16*)wev)[p]);
  int pos = rpe[e] + atomicAdd(&cnte[e], 1);
  int2 t1; t1.x = v; t1.y = __float_as_int(w1);
  ente[pos] = t1;
  pos = rpv[v] + atomicAdd(&cntv[v], 1);
  int2 t2; t2.x = e; t2.y = __float_as_int(w2);
  entv[pos] = t2;
}

// ---------------- GEMM: x = feats @ W + b (bf16 MFMA, bf16 out) ----------------

__global__ void transpose_w_kernel(const void* __restrict__ W, u16* __restrict__ WT,
                                   const int* __restrict__ flag) {
  int idx = blockIdx.x * 256 + threadIdx.x;  // 256*128 = 32768 elems
  u16 v = (*flag) ? (u16)f2bf_rne(((const float*)W)[idx]) : ((const u16*)W)[idx];
  WT[(idx & 127) * 256 + (idx >> 7)] = v;
}

template <bool FP32>
__global__ __launch_bounds__(256) void gemm_kernel(
    const void* __restrict__ A,    // feats [N][256] (bf16 or fp32 per flag)
    const u16* __restrict__ WT,    // bf16 [128][256] (W transposed, canonical)
    const void* __restrict__ bias, // [128]
    const int* __restrict__ flag,
    u16* __restrict__ xb) {        // bf16 [N][128]
  if ((*flag != 0) != FP32) return;
  __shared__ u16 wt[32768];
  {
    const uint4* src = (const uint4*)WT;  // 4096 granules, 32 per row
    uint4* d = (uint4*)wt;
    for (int i = threadIdx.x; i < 4096; i += 256) {
      int r = i >> 5, g = i & 31;
      d[(r << 5) | (g ^ (r & 31))] = src[i];
    }
  }
  __syncthreads();
  int lane = threadIdx.x & 63;
  int q = lane >> 4, m = lane & 15;
  int wave0 = blockIdx.x * 4 + (threadIdx.x >> 6);
  int nwaves = gridDim.x * 4;
  const s16x8* wlds = (const s16x8*)wt;
  for (int strip = wave0; strip < HG_N / 16; strip += nwaves) {
    f32x4 acc[8];
#pragma unroll
    for (int n = 0; n < 8; ++n) acc[n] = (f32x4){0.f, 0.f, 0.f, 0.f};
#pragma unroll
    for (int k0 = 0; k0 < 8; ++k0) {
      s16x8 a;
      if (FP32) {
        const float* ar = (const float*)A + (size_t)(strip * 16 + m) * 256 + q * 8 + k0 * 32;
        float4 p0 = *(const float4*)ar;
        float4 p1 = *(const float4*)(ar + 4);
        a[0] = (short)f2bf_rne(p0.x); a[1] = (short)f2bf_rne(p0.y);
        a[2] = (short)f2bf_rne(p0.z); a[3] = (short)f2bf_rne(p0.w);
        a[4] = (short)f2bf_rne(p1.x); a[5] = (short)f2bf_rne(p1.y);
        a[6] = (short)f2bf_rne(p1.z); a[7] = (short)f2bf_rne(p1.w);
      } else {
        a = *(const s16x8*)((const u16*)A + (size_t)(strip * 16 + m) * 256 + q * 8 + k0 * 32);
      }
      int g = (k0 << 2) | q;
#pragma unroll
      for (int n = 0; n < 8; ++n) {
        int rr = n * 16 + m;  // B col index; WT row
        s16x8 b = wlds[(rr << 5) | (g ^ (rr & 31))];  // B[k0*32+q*8+j][rr]
        acc[n] = __builtin_amdgcn_mfma_f32_16x16x32_bf16(a, b, acc[n], 0, 0, 0);
      }
    }
#pragma unroll
    for (int n = 0; n < 8; ++n) {
      float bv = FP32 ? ((const float*)bias)[n * 16 + m] : bf2f(((const u16*)bias)[n * 16 + m]);
#pragma unroll
      for (int r = 0; r < 4; ++r) {
        // C/D layout: col = lane&15, row = (lane>>4)*4 + r  [m89/m91 verified]
        xb[(size_t)(strip * 16 + q * 4 + r) * 128 + n * 16 + m] = (u16)f2bf_rne(acc[n][r] + bv);
      }
    }
  }
}

// ---------------- Pull aggregation over bf16 rows, fp32 accumulate ----------------
// 4-way unrolled: 4 packed-entry loads then 4 independent 256B wave-gathers in
// flight before the FMAs (MLP x4 vs the serial loop).

__global__ __launch_bounds__(256) void pull_kernel(
    const int* __restrict__ rp, const int2* __restrict__ ent,
    const u32* __restrict__ src, u32* __restrict__ dst, int nrows) {
  int row = blockIdx.x * 4 + (threadIdx.x >> 6);
  if (row >= nrows) return;
  int lane = threadIdx.x & 63;
  int beg = rp[row], end = rp[row + 1];
  float ax = 0.f, ay = 0.f, den = 0.f;
  int j = beg;
  for (; j + 4 <= end; j += 4) {
    int2 e0 = ent[j], e1 = ent[j + 1], e2 = ent[j + 2], e3 = ent[j + 3];
    u32 u0 = src[(size_t)e0.x * 64 + lane];
    u32 u1 = src[(size_t)e1.x * 64 + lane];
    u32 u2 = src[(size_t)e2.x * 64 + lane];
    u32 u3 = src[(size_t)e3.x * 64 + lane];
    float w0 = __int_as_float(e0.y), w1 = __int_as_float(e1.y);
    float w2 = __int_as_float(e2.y), w3 = __int_as_float(e3.y);
    den += (w0 + w1) + (w2 + w3);
    ax = fmaf(w0, bf_lo(u0), ax); ay = fmaf(w0, bf_hi(u0), ay);
    ax = fmaf(w1, bf_lo(u1), ax); ay = fmaf(w1, bf_hi(u1), ay);
    ax = fmaf(w2, bf_lo(u2), ax); ay = fmaf(w2, bf_hi(u2), ay);
    ax = fmaf(w3, bf_lo(u3), ax); ay = fmaf(w3, bf_hi(u3), ay);
  }
  for (; j < end; ++j) {
    int2 e0 = ent[j];
    u32 u0 = src[(size_t)e0.x * 64 + lane];
    float w0 = __int_as_float(e0.y);
    den += w0;
    ax = fmaf(w0, bf_lo(u0), ax);
    ay = fmaf(w0, bf_hi(u0), ay);
  }
  float inv = 1.0f / fmaxf(den, 1e-12f);
  dst[(size_t)row * 64 + lane] = f2bf_rne(ax * inv) | (f2bf_rne(ay * inv) << 16);
}

// ---------------- Softmax (bf16 in, bf16/fp32 out) ----------------

template <bool FP32>
__global__ __launch_bounds__(256) void softmax_kernel(const u32* __restrict__ xb,
                                                      void* __restrict__ out,
                                                      const int* __restrict__ flag) {
  if ((*flag != 0) != FP32) return;
  int row = blockIdx.x * 4 + (threadIdx.x >> 6);
  int lane = threadIdx.x & 63;
  u32 u = xb[(size_t)row * 64 + lane];
  float v0 = __uint_as_float(u << 16);
  float v1 = __uint_as_float(u & 0xffff0000u);
  float mx = fmaxf(v0, v1);
#pragma unroll
  for (int off = 32; off; off >>= 1) mx = fmaxf(mx, __shfl_xor(mx, off));
  float e0 = __expf(v0 - mx), e1 = __expf(v1 - mx);
  float s = e0 + e1;
#pragma unroll
  for (int off = 32; off; off >>= 1) s += __shfl_xor(s, off);
  float inv = 1.0f / s;
  if (FP32) {
    float2 o; o.x = e0 * inv; o.y = e1 * inv;
    ((float2*)out)[(size_t)row * 64 + lane] = o;
  } else {
    ((u32*)out)[(size_t)row * 64 + lane] = f2bf_rne(e0 * inv) | (f2bf_rne(e1 * inv) << 16);
  }
}

// ---------------- launch ----------------

extern "C" void kernel_launch(void* const* d_in, const int* in_sizes, int n_in,
                              void* d_out, int out_size, void* d_ws, size_t ws_size,
                              hipStream_t stream) {
  const void* feats = d_in[0];
  const void* W = d_in[1];
  const void* bias = d_in[2];
  const void* wve = d_in[3];
  const void* wev = d_in[4];
  const int* pv = (const int*)d_in[5];
  const int* pe = (const int*)d_in[6];

  char* p = (char*)d_ws;
  auto alloc = [&](size_t b) { char* r = p; p += (b + 255) & ~(size_t)255; return r; };
  int* flag = (int*)alloc(4);
  u16* xb = (u16*)alloc((size_t)HG_N * HG_D * 2);   // vertex features bf16
  u16* yb = (u16*)alloc((size_t)HG_E * HG_D * 2);   // edge features bf16
  u16* wtg = (u16*)alloc(HG_D * HG_F * 2);          // canonical W^T bf16
  int* rpe = (int*)alloc((HG_E + 1) * 4);
  int* rpv = (int*)alloc((HG_N + 1) * 4);
  int* cnte = (int*)alloc(HG_E * 4);
  int* cntv = (int*)alloc(HG_N * 4);
  int2* ente = (int2*)alloc((size_t)HG_NNZ * 8);    // packed edge-CSR entries
  int2* entv = (int2*)alloc((size_t)HG_NNZ * 8);    // packed vertex-CSR entries
  int* bsums = (int*)alloc(4096);
  // total ~98 MB

  detect_dtype<<<1, 256, 0, stream>>>((const u16*)feats, flag);

  // CSR build
  hipMemsetAsync(cnte, 0, HG_E * 4, stream);
  hipMemsetAsync(cntv, 0, HG_N * 4, stream);
  hist_kernel<<<(HG_NNZ + 255) / 256, 256, 0, stream>>>(pv, pe, cntv, cnte);
  int be = (HG_E + 1023) / 1024, bv = (HG_N + 1023) / 1024;
  scan_pass1<<<be, 256, 0, stream>>>(cnte, HG_E, bsums);
  scan_pass2<<<1, 256, 0, stream>>>(bsums, be);
  scan_pass3<<<be, 256, 0, stream>>>(cnte, HG_E, bsums, rpe, HG_NNZ);
  scan_pass1<<<bv, 256, 0, stream>>>(cntv, HG_N, bsums);
  scan_pass2<<<1, 256, 0, stream>>>(bsums, bv);
  scan_pass3<<<bv, 256, 0, stream>>>(cntv, HG_N, bsums, rpv, HG_NNZ);
  hipMemsetAsync(cnte, 0, HG_E * 4, stream);
  hipMemsetAsync(cntv, 0, HG_N * 4, stream);
  build_csr<<<(HG_NNZ + 255) / 256, 256, 0, stream>>>(pv, pe, wve, wev, rpe, rpv,
                                                      cnte, cntv, ente, entv, flag);

  // x = feats @ W + b
  transpose_w_kernel<<<128, 256, 0, stream>>>(W, wtg, flag);
  gemm_kernel<false><<<1024, 256, 0, stream>>>(feats, wtg, bias, flag, xb);
  gemm_kernel<true><<<1024, 256, 0, stream>>>(feats, wtg, bias, flag, xb);

  // two hops of weighted-mean aggregation (xb and yb ping-pong)
  pull_kernel<<<HG_E / 4, 256, 0, stream>>>(rpe, ente, (const u32*)xb, (u32*)yb, HG_E);
  pull_kernel<<<HG_N / 4, 256, 0, stream>>>(rpv, entv, (const u32*)yb, (u32*)xb, HG_N);
  pull_kernel<<<HG_E / 4, 256, 0, stream>>>(rpe, ente, (const u32*)xb, (u32*)yb, HG_E);
  pull_kernel<<<HG_N / 4, 256, 0, stream>>>(rpv, entv, (const u32*)yb, (u32*)xb, HG_N);

  softmax_kernel<false><<<HG_N / 4, 256, 0, stream>>>((const u32*)xb, d_out, flag);
  softmax_kernel<true><<<HG_N / 4, 256, 0, stream>>>((const u32*)xb, d_out, flag);
}